// Round 13
// baseline (246.945 us; speedup 1.0000x reference)
//
#include <hip/hip_runtime.h>
#include <hip/hip_fp16.h>

#define IN_F 128
#define H_F 64
#define C_F 16
#define BUCKET 256          // nodes per bucket (binning granularity)
#define BSH 8               // log2(BUCKET)
#define MAXB 512            // hist/scan capacity (>= nBuckets = ceil(N/256))
#define EPB 8192            // edges per binning block
#define NB_AGG 1024         // k_agg blocks (grid-stride)
#define NRED 64             // stage-1 reduction blocks

// ---------------- fused bucket histograms (src + dst), no per-node atomics ----------
__global__ __launch_bounds__(256) void k_bhist(const int* __restrict__ src,
                                               const int* __restrict__ dst,
                                               int* __restrict__ cntS,
                                               int* __restrict__ cntD, int E, int nb) {
    __shared__ int hs[MAXB];
    __shared__ int hd[MAXB];
    const int tid = threadIdx.x;
    for (int i = tid; i < MAXB; i += 256) { hs[i] = 0; hd[i] = 0; }
    __syncthreads();
    const int start = blockIdx.x * EPB;
    for (int k = 0; k < EPB / 256; ++k) {
        int e = start + (k << 8) + tid;
        if (e < E) {
            atomicAdd(&hs[src[e] >> BSH], 1);
            atomicAdd(&hd[dst[e] >> BSH], 1);
        }
    }
    __syncthreads();
    for (int b = tid; b < nb; b += 256) {
        int s = hs[b], d = hd[b];
        if (s) atomicAdd(&cntS[b], s);
        if (d) atomicAdd(&cntD[b], d);
    }
}

// ------------- exclusive scans of BOTH bucket-count arrays (single block) -------------
__global__ __launch_bounds__(1024) void k_bucketscan2(const int* __restrict__ cntD,
                                                      const int* __restrict__ cntS,
                                                      int* __restrict__ baseD,
                                                      int* __restrict__ curD,
                                                      int* __restrict__ baseS,
                                                      int* __restrict__ curS,
                                                      int nb, int E) {
    __shared__ int s[1024];
    const int t = threadIdx.x;
    for (int pass = 0; pass < 2; ++pass) {
        const int* cnt = pass ? cntS : cntD;
        int* base = pass ? baseS : baseD;
        int* cur  = pass ? curS  : curD;
        int i0 = 2 * t, i1 = 2 * t + 1;
        int v0 = (i0 < nb) ? cnt[i0] : 0;
        int v1 = (i1 < nb) ? cnt[i1] : 0;
        int pair = v0 + v1;
        s[t] = pair;
        __syncthreads();
        for (int off = 1; off < 1024; off <<= 1) {
            int x = (t >= off) ? s[t - off] : 0;
            __syncthreads();
            s[t] += x;
            __syncthreads();
        }
        int excl = s[t] - pair;
        if (i0 < nb) { base[i0] = excl;      cur[i0] = excl; }
        if (i1 < nb) { base[i1] = excl + v0; cur[i1] = excl + v0; }
        if (t == 0) base[nb] = E;
        __syncthreads();
    }
}

// ------------- fused dual binning: by dst (pay=src) AND by src (pay=dst) --------------
// code = (klocal << 17) | payload   (klocal < 256, payload < 2^17)
__global__ __launch_bounds__(256) void k_bin2(const int* __restrict__ src,
                                              const int* __restrict__ dst,
                                              int* __restrict__ gCurD,
                                              int* __restrict__ gCurS,
                                              unsigned int* __restrict__ binnedD,
                                              unsigned int* __restrict__ binnedS,
                                              int E, int nb) {
    __shared__ int hd[MAXB], hs[MAXB];
    __shared__ int bd[MAXB], bs[MAXB];
    __shared__ int cd[MAXB], cs[MAXB];
    const int tid = threadIdx.x;
    const int start = blockIdx.x * EPB;
    for (int i = tid; i < MAXB; i += 256) { hd[i] = 0; hs[i] = 0; cd[i] = 0; cs[i] = 0; }
    __syncthreads();
    for (int k = 0; k < EPB / 256; ++k) {
        int e = start + (k << 8) + tid;
        if (e < E) {
            atomicAdd(&hd[dst[e] >> BSH], 1);
            atomicAdd(&hs[src[e] >> BSH], 1);
        }
    }
    __syncthreads();
    for (int b = tid; b < nb; b += 256) {
        if (hd[b]) bd[b] = atomicAdd(&gCurD[b], hd[b]);
        if (hs[b]) bs[b] = atomicAdd(&gCurS[b], hs[b]);
    }
    __syncthreads();
    for (int k = 0; k < EPB / 256; ++k) {
        int e = start + (k << 8) + tid;
        if (e < E) {
            int sv = src[e], dv = dst[e];
            int b1 = dv >> BSH;
            int p1 = bd[b1] + atomicAdd(&cd[b1], 1);
            binnedD[p1] = ((unsigned)(dv & (BUCKET - 1)) << 17) | (unsigned)sv;
            int b2 = sv >> BSH;
            int p2 = bs[b2] + atomicAdd(&cs[b2], 1);
            binnedS[p2] = ((unsigned)(sv & (BUCKET - 1)) << 17) | (unsigned)dv;
        }
    }
}

// ---- per-bucket counting sort of binnedD -> CSR (sortedSrc + nodeOff) + norm_in ------
// block = 256-node dst-bucket, 256 threads = 4 waves. Two streaming passes, no staging.
__global__ __launch_bounds__(256) void k_sortD(const unsigned int* __restrict__ binnedD,
                                               const int* __restrict__ baseD,
                                               int* __restrict__ sortedSrc,
                                               int* __restrict__ nodeOff,
                                               float* __restrict__ norm_in,
                                               int N, int E) {
    __shared__ int hist[BUCKET];
    __shared__ int cur[BUCKET];
    __shared__ int wtot[4];
    const int tid = threadIdx.x, lane = tid & 63, wave = tid >> 6;
    const int b = blockIdx.x;
    const int s0 = baseD[b], s1 = baseD[b + 1];

    hist[tid] = 0;
    __syncthreads();
    for (int i = s0 + tid; i < s1; i += 256)
        atomicAdd(&hist[binnedD[i] >> 17], 1);
    __syncthreads();

    // 256-wide exclusive scan (4-wave shfl)
    int v = hist[tid];
    int inc = v;
#pragma unroll
    for (int off = 1; off < 64; off <<= 1) {
        int t2 = __shfl_up(inc, off);
        if (lane >= off) inc += t2;
    }
    if (lane == 63) wtot[wave] = inc;
    __syncthreads();
    int add = 0;
#pragma unroll
    for (int w2 = 0; w2 < 4; ++w2)
        if (w2 < wave) add += wtot[w2];
    int excl = add + inc - v;
    cur[tid] = s0 + excl;
    int gn = b * BUCKET + tid;
    if (gn < N) {
        nodeOff[gn] = s0 + excl;
        norm_in[gn] = 1.0f / sqrtf((float)max(v, 1));
        if (gn == N - 1) nodeOff[N] = E;
    }
    __syncthreads();

    for (int i = s0 + tid; i < s1; i += 256) {
        unsigned c = binnedD[i];
        int p = atomicAdd(&cur[c >> 17], 1);
        sortedSrc[p] = (int)(c & 0x1FFFFu);
    }
}

// ---------------- wsum + norm_out from binnedS (per src-bucket) ----------------
__global__ __launch_bounds__(256) void k_wsum(const unsigned int* __restrict__ binnedS,
                                              const int* __restrict__ baseS,
                                              const float* __restrict__ norm_in,
                                              float* __restrict__ wsum,
                                              float* __restrict__ norm_out, int N) {
    __shared__ float wloc[BUCKET];
    __shared__ int hist[BUCKET];
    const int tid = threadIdx.x;
    wloc[tid] = 0.0f;
    hist[tid] = 0;
    __syncthreads();
    const int b = blockIdx.x;
    const int s0 = baseS[b], s1 = baseS[b + 1];
    for (int i = s0 + tid; i < s1; i += 256) {
        unsigned c = binnedS[i];
        int sl = (int)(c >> 17);
        float ni = norm_in[c & 0x1FFFFu];
        atomicAdd(&hist[sl], 1);
        atomicAdd(&wloc[sl], ni);
    }
    __syncthreads();
    int gn = b * BUCKET + tid;
    if (gn < N) {
        norm_out[gn] = 1.0f / sqrtf((float)max(hist[tid], 1));
        wsum[gn] = wloc[tid];
    }
}

// ------- layer 1 GEMM: X1q = fp8_e4m3((in_feat @ W1) * norm_out), [N,64] bytes -------
__global__ __launch_bounds__(256) void k_gemm1(const float* __restrict__ in_feat,
                                               const float* __restrict__ W1,
                                               const float* __restrict__ norm_out,
                                               unsigned char* __restrict__ X1q, int N) {
    __shared__ float Wl[IN_F][H_F];       // 32 KB
    __shared__ float Al[64][IN_F + 4];    // 33 KB
    const int t = threadIdx.x;
    const int base = blockIdx.x * 64;

    for (int i = t; i < IN_F * H_F / 4; i += 256)
        ((float4*)&Wl[0][0])[i] = ((const float4*)W1)[i];
    for (int i = t; i < 64 * IN_F / 4; i += 256) {
        int n = i >> 5;
        int k4 = i & 31;
        int gn = base + n;
        float4 v = make_float4(0.f, 0.f, 0.f, 0.f);
        if (gn < N) v = ((const float4*)(in_feat + (size_t)gn * IN_F))[k4];
        *(float4*)&Al[n][k4 * 4] = v;
    }
    __syncthreads();

    const int c4 = (t & 15) * 4;
    const int r4 = (t >> 4) * 4;
    float acc[4][4] = {};
#pragma unroll 4
    for (int k = 0; k < IN_F; k += 4) {
        float4 w0 = *(const float4*)&Wl[k + 0][c4];
        float4 w1 = *(const float4*)&Wl[k + 1][c4];
        float4 w2 = *(const float4*)&Wl[k + 2][c4];
        float4 w3 = *(const float4*)&Wl[k + 3][c4];
        const float* wp0 = (const float*)&w0;
        const float* wp1 = (const float*)&w1;
        const float* wp2 = (const float*)&w2;
        const float* wp3 = (const float*)&w3;
#pragma unroll
        for (int i = 0; i < 4; ++i) {
            float4 a = *(const float4*)&Al[r4 + i][k];
#pragma unroll
            for (int jj = 0; jj < 4; ++jj)
                acc[i][jj] = fmaf(a.x, wp0[jj],
                             fmaf(a.y, wp1[jj],
                             fmaf(a.z, wp2[jj],
                             fmaf(a.w, wp3[jj], acc[i][jj]))));
        }
    }
#pragma unroll
    for (int i = 0; i < 4; ++i) {
        int n = base + r4 + i;
        if (n < N) {
            float no = norm_out[n];
            int pk = 0;
            pk = __builtin_amdgcn_cvt_pk_fp8_f32(acc[i][0] * no, acc[i][1] * no, pk, false);
            pk = __builtin_amdgcn_cvt_pk_fp8_f32(acc[i][2] * no, acc[i][3] * no, pk, true);
            *(int*)&X1q[(size_t)n * H_F + c4] = pk;
        }
    }
}

// ---- CSR aggregation: wave = node, lane = feature, 8-deep fp8 row gathers ----------
// grid-stride over nodes; ~1 KB LDS -> wave-slot-limited occupancy.
__global__ __launch_bounds__(256) void k_agg(const unsigned char* __restrict__ X1q,
                                             const int* __restrict__ sortedSrc,
                                             const int* __restrict__ nodeOff,
                                             const float* __restrict__ norm_in,
                                             const float* __restrict__ norm_out,
                                             const float* __restrict__ wsum,
                                             const float* __restrict__ b1,
                                             float* __restrict__ partials, int N) {
    const int lane = threadIdx.x & 63, wave = threadIdx.x >> 6;
    const float bj = b1[lane];
    const int gw = blockIdx.x * 4 + wave;
    const int nw = NB_AGG * 4;
    float hacc = 0.0f;
    for (int n = gw; n < N; n += nw) {
        int s0 = nodeOff[n], s1 = nodeOff[n + 1];
        float acc = 0.0f;
        int e = s0;
        for (; e + 7 < s1; e += 8) {
            int ss[8]; unsigned qq[8];
#pragma unroll
            for (int u = 0; u < 8; ++u) ss[u] = sortedSrc[e + u];
#pragma unroll
            for (int u = 0; u < 8; ++u) qq[u] = X1q[(size_t)ss[u] * H_F + lane];
#pragma unroll
            for (int u = 0; u < 8; ++u) acc += __builtin_amdgcn_cvt_f32_fp8(qq[u], 0);
        }
        for (; e < s1; ++e) {
            unsigned q = X1q[(size_t)sortedSrc[e] * H_F + lane];
            acc += __builtin_amdgcn_cvt_f32_fp8(q, 0);
        }
        float v = acc * norm_in[n] + bj;
        hacc = fmaf(v > 0.0f ? v : 0.0f, norm_out[n] * wsum[n], hacc);
    }
    __shared__ float hl[4][64];
    hl[wave][lane] = hacc;
    __syncthreads();
    if (wave == 0)
        partials[(size_t)blockIdx.x * 64 + lane] =
            (hl[0][lane] + hl[1][lane]) + (hl[2][lane] + hl[3][lane]);
}

// ---------------- stage-1 reduction: partials[nbp][64] -> red[NRED][64] (f64) ----------
__global__ __launch_bounds__(256) void k_red(const float* __restrict__ partials,
                                             double* __restrict__ red, int nbp) {
    const int lane = threadIdx.x & 63, wave = threadIdx.x >> 6;
    const int rpb = (nbp + NRED - 1) / NRED;
    const int r0 = blockIdx.x * rpb;
    int r1 = r0 + rpb; if (r1 > nbp) r1 = nbp;
    double s = 0.0;
    for (int r = r0 + wave; r < r1; r += 4)
        s += (double)partials[(size_t)r * 64 + lane];
    __shared__ double sd[4][64];
    sd[wave][lane] = s;
    __syncthreads();
    if (wave == 0)
        red[(size_t)blockIdx.x * 64 + lane] =
            (sd[0][lane] + sd[1][lane]) + (sd[2][lane] + sd[3][lane]);
}

// ---------------- final: red (f64) -> out = hsum@W2/N + b2 ----------------
__global__ __launch_bounds__(256) void k_final(const double* __restrict__ red,
                                               const float* __restrict__ W2,
                                               const float* __restrict__ b2,
                                               float* __restrict__ out, int N) {
    __shared__ double hs[4][64];
    const int sub = threadIdx.x >> 6;   // 0..3
    const int j   = threadIdx.x & 63;
    double s = 0.0;
    for (int p = sub; p < NRED; p += 4)
        s += red[(size_t)p * 64 + j];
    hs[sub][j] = s;
    __syncthreads();
    if (threadIdx.x < C_F) {
        int c = threadIdx.x;
        double o = 0.0;
        for (int k = 0; k < 64; ++k) {
            double hk = hs[0][k] + hs[1][k] + hs[2][k] + hs[3][k];
            o += hk * (double)W2[k * C_F + c];
        }
        out[c] = (float)(o / (double)N + (double)b2[c]);
    }
}

extern "C" void kernel_launch(void* const* d_in, const int* in_sizes, int n_in,
                              void* d_out, int out_size, void* d_ws, size_t ws_size,
                              hipStream_t stream) {
    const float* in_feat = (const float*)d_in[0];
    const int*   src     = (const int*)d_in[1];
    const int*   dst     = (const int*)d_in[2];
    const float* W1      = (const float*)d_in[3];
    const float* b1      = (const float*)d_in[4];
    const float* W2      = (const float*)d_in[5];
    const float* b2      = (const float*)d_in[6];
    float* out = (float*)d_out;

    const int N = in_sizes[0] / IN_F;           // 100000
    const int E = in_sizes[1];                  // 1600000
    const int nb = (N + BUCKET - 1) / BUCKET;   // 391 (<= MAXB)
    const int nBin = (E + EPB - 1) / EPB;       // 196

    // ---- workspace layout (4B units) ----
    unsigned int* binnedD = (unsigned int*)d_ws;         // E
    unsigned int* binnedS = binnedD + E;                 // E
    int*   sortedSrc = (int*)(binnedS + E);              // E
    int*   cntD   = sortedSrc + E;                       // MAXB  \ zeroed
    int*   cntS   = cntD + MAXB;                         // MAXB  /
    int*   baseD  = cntS + MAXB;                         // MAXB+1
    int*   curD   = baseD + MAXB + 1;                    // MAXB
    int*   baseS  = curD + MAXB;                         // MAXB+1
    int*   curS   = baseS + MAXB + 1;                    // MAXB
    int*   nodeOff  = curS + MAXB;                       // N+1
    float* norm_in  = (float*)(nodeOff + N + 1);         // N
    float* norm_out = norm_in + N;                       // N
    float* wsum     = norm_out + N;                      // N
    unsigned char* X1q = (unsigned char*)(wsum + N);     // 64N bytes
    float* partials = (float*)(X1q + 64 * (size_t)N);    // NB_AGG*64
    double* red     = (double*)(partials + (size_t)NB_AGG * 64);  // NRED*64 f64

    // only the bucket-count accumulators are read-before-write
    hipMemsetAsync(cntD, 0, 2 * MAXB * sizeof(int), stream);

    k_bhist<<<nBin, 256, 0, stream>>>(src, dst, cntS, cntD, E, nb);

    k_bucketscan2<<<1, 1024, 0, stream>>>(cntD, cntS, baseD, curD, baseS, curS, nb, E);

    k_bin2<<<nBin, 256, 0, stream>>>(src, dst, curD, curS, binnedD, binnedS, E, nb);

    k_sortD<<<nb, 256, 0, stream>>>(binnedD, baseD, sortedSrc, nodeOff, norm_in, N, E);
    k_wsum <<<nb, 256, 0, stream>>>(binnedS, baseS, norm_in, wsum, norm_out, N);

    k_gemm1<<<(N + 63) / 64, 256, 0, stream>>>(in_feat, W1, norm_out, X1q, N);

    k_agg<<<NB_AGG, 256, 0, stream>>>(X1q, sortedSrc, nodeOff, norm_in, norm_out,
                                      wsum, b1, partials, N);

    k_red  <<<NRED, 256, 0, stream>>>(partials, red, NB_AGG);
    k_final<<<1, 256, 0, stream>>>(red, W2, b2, out, N);
}

// Round 14
// 200.199 us; speedup vs baseline: 1.2335x; 1.2335x over previous
//
#include <hip/hip_runtime.h>
#include <hip/hip_fp16.h>

#define IN_F 128
#define H_F 64
#define C_F 16
#define BUCKET 256          // nodes per bucket (binning granularity)
#define BSH 8               // log2(BUCKET)
#define MAXB 512            // hist/scan capacity (>= nBuckets = ceil(N/256))
#define EPB 8192            // edges per binning block
#define AGG_W 64            // nodes per k_agg block (window)
#define CAP 2048            // staged indices per k_agg block (8 KB)
#define NRED 64             // stage-1 reduction blocks

// ---------------- fused bucket histograms (src + dst), no per-node atomics ----------
__global__ __launch_bounds__(256) void k_bhist(const int* __restrict__ src,
                                               const int* __restrict__ dst,
                                               int* __restrict__ cntS,
                                               int* __restrict__ cntD, int E, int nb) {
    __shared__ int hs[MAXB];
    __shared__ int hd[MAXB];
    const int tid = threadIdx.x;
    for (int i = tid; i < MAXB; i += 256) { hs[i] = 0; hd[i] = 0; }
    __syncthreads();
    const int start = blockIdx.x * EPB;
    for (int k = 0; k < EPB / 256; ++k) {
        int e = start + (k << 8) + tid;
        if (e < E) {
            atomicAdd(&hs[src[e] >> BSH], 1);
            atomicAdd(&hd[dst[e] >> BSH], 1);
        }
    }
    __syncthreads();
    for (int b = tid; b < nb; b += 256) {
        int s = hs[b], d = hd[b];
        if (s) atomicAdd(&cntS[b], s);
        if (d) atomicAdd(&cntD[b], d);
    }
}

// ------------- exclusive scans of BOTH bucket-count arrays (single block) -------------
__global__ __launch_bounds__(1024) void k_bucketscan2(const int* __restrict__ cntD,
                                                      const int* __restrict__ cntS,
                                                      int* __restrict__ baseD,
                                                      int* __restrict__ curD,
                                                      int* __restrict__ baseS,
                                                      int* __restrict__ curS,
                                                      int nb, int E) {
    __shared__ int s[1024];
    const int t = threadIdx.x;
    for (int pass = 0; pass < 2; ++pass) {
        const int* cnt = pass ? cntS : cntD;
        int* base = pass ? baseS : baseD;
        int* cur  = pass ? curS  : curD;
        int i0 = 2 * t, i1 = 2 * t + 1;
        int v0 = (i0 < nb) ? cnt[i0] : 0;
        int v1 = (i1 < nb) ? cnt[i1] : 0;
        int pair = v0 + v1;
        s[t] = pair;
        __syncthreads();
        for (int off = 1; off < 1024; off <<= 1) {
            int x = (t >= off) ? s[t - off] : 0;
            __syncthreads();
            s[t] += x;
            __syncthreads();
        }
        int excl = s[t] - pair;
        if (i0 < nb) { base[i0] = excl;      cur[i0] = excl; }
        if (i1 < nb) { base[i1] = excl + v0; cur[i1] = excl + v0; }
        if (t == 0) base[nb] = E;
        __syncthreads();
    }
}

// ------------- fused dual binning: by dst (pay=src) AND by src (pay=dst) --------------
// code = (klocal << 17) | payload   (klocal < 256, payload < 2^17)
__global__ __launch_bounds__(256) void k_bin2(const int* __restrict__ src,
                                              const int* __restrict__ dst,
                                              int* __restrict__ gCurD,
                                              int* __restrict__ gCurS,
                                              unsigned int* __restrict__ binnedD,
                                              unsigned int* __restrict__ binnedS,
                                              int E, int nb) {
    __shared__ int hd[MAXB], hs[MAXB];
    __shared__ int bd[MAXB], bs[MAXB];
    __shared__ int cd[MAXB], cs[MAXB];
    const int tid = threadIdx.x;
    const int start = blockIdx.x * EPB;
    for (int i = tid; i < MAXB; i += 256) { hd[i] = 0; hs[i] = 0; cd[i] = 0; cs[i] = 0; }
    __syncthreads();
    for (int k = 0; k < EPB / 256; ++k) {
        int e = start + (k << 8) + tid;
        if (e < E) {
            atomicAdd(&hd[dst[e] >> BSH], 1);
            atomicAdd(&hs[src[e] >> BSH], 1);
        }
    }
    __syncthreads();
    for (int b = tid; b < nb; b += 256) {
        if (hd[b]) bd[b] = atomicAdd(&gCurD[b], hd[b]);
        if (hs[b]) bs[b] = atomicAdd(&gCurS[b], hs[b]);
    }
    __syncthreads();
    for (int k = 0; k < EPB / 256; ++k) {
        int e = start + (k << 8) + tid;
        if (e < E) {
            int sv = src[e], dv = dst[e];
            int b1 = dv >> BSH;
            int p1 = bd[b1] + atomicAdd(&cd[b1], 1);
            binnedD[p1] = ((unsigned)(dv & (BUCKET - 1)) << 17) | (unsigned)sv;
            int b2 = sv >> BSH;
            int p2 = bs[b2] + atomicAdd(&cs[b2], 1);
            binnedS[p2] = ((unsigned)(sv & (BUCKET - 1)) << 17) | (unsigned)dv;
        }
    }
}

// ---- per-bucket counting sort of binnedD -> CSR (sortedSrc + nodeOff) + norm_in ------
__global__ __launch_bounds__(256) void k_sortD(const unsigned int* __restrict__ binnedD,
                                               const int* __restrict__ baseD,
                                               int* __restrict__ sortedSrc,
                                               int* __restrict__ nodeOff,
                                               float* __restrict__ norm_in,
                                               int N, int E) {
    __shared__ int hist[BUCKET];
    __shared__ int cur[BUCKET];
    __shared__ int wtot[4];
    const int tid = threadIdx.x, lane = tid & 63, wave = tid >> 6;
    const int b = blockIdx.x;
    const int s0 = baseD[b], s1 = baseD[b + 1];

    hist[tid] = 0;
    __syncthreads();
    for (int i = s0 + tid; i < s1; i += 256)
        atomicAdd(&hist[binnedD[i] >> 17], 1);
    __syncthreads();

    int v = hist[tid];
    int inc = v;
#pragma unroll
    for (int off = 1; off < 64; off <<= 1) {
        int t2 = __shfl_up(inc, off);
        if (lane >= off) inc += t2;
    }
    if (lane == 63) wtot[wave] = inc;
    __syncthreads();
    int add = 0;
#pragma unroll
    for (int w2 = 0; w2 < 4; ++w2)
        if (w2 < wave) add += wtot[w2];
    int excl = add + inc - v;
    cur[tid] = s0 + excl;
    int gn = b * BUCKET + tid;
    if (gn < N) {
        nodeOff[gn] = s0 + excl;
        norm_in[gn] = 1.0f / sqrtf((float)max(v, 1));
        if (gn == N - 1) nodeOff[N] = E;
    }
    __syncthreads();

    for (int i = s0 + tid; i < s1; i += 256) {
        unsigned c = binnedD[i];
        int p = atomicAdd(&cur[c >> 17], 1);
        sortedSrc[p] = (int)(c & 0x1FFFFu);
    }
}

// ---------------- wsum + norm_out from binnedS (per src-bucket) ----------------
__global__ __launch_bounds__(256) void k_wsum(const unsigned int* __restrict__ binnedS,
                                              const int* __restrict__ baseS,
                                              const float* __restrict__ norm_in,
                                              float* __restrict__ wsum,
                                              float* __restrict__ norm_out, int N) {
    __shared__ float wloc[BUCKET];
    __shared__ int hist[BUCKET];
    const int tid = threadIdx.x;
    wloc[tid] = 0.0f;
    hist[tid] = 0;
    __syncthreads();
    const int b = blockIdx.x;
    const int s0 = baseS[b], s1 = baseS[b + 1];
    for (int i = s0 + tid; i < s1; i += 256) {
        unsigned c = binnedS[i];
        int sl = (int)(c >> 17);
        float ni = norm_in[c & 0x1FFFFu];
        atomicAdd(&hist[sl], 1);
        atomicAdd(&wloc[sl], ni);
    }
    __syncthreads();
    int gn = b * BUCKET + tid;
    if (gn < N) {
        norm_out[gn] = 1.0f / sqrtf((float)max(hist[tid], 1));
        wsum[gn] = wloc[tid];
    }
}

// ------- layer 1 GEMM: X1q = fp8_e4m3((in_feat @ W1) * norm_out), [N,64] bytes -------
__global__ __launch_bounds__(256) void k_gemm1(const float* __restrict__ in_feat,
                                               const float* __restrict__ W1,
                                               const float* __restrict__ norm_out,
                                               unsigned char* __restrict__ X1q, int N) {
    __shared__ float Wl[IN_F][H_F];       // 32 KB
    __shared__ float Al[64][IN_F + 4];    // 33 KB
    const int t = threadIdx.x;
    const int base = blockIdx.x * 64;

    for (int i = t; i < IN_F * H_F / 4; i += 256)
        ((float4*)&Wl[0][0])[i] = ((const float4*)W1)[i];
    for (int i = t; i < 64 * IN_F / 4; i += 256) {
        int n = i >> 5;
        int k4 = i & 31;
        int gn = base + n;
        float4 v = make_float4(0.f, 0.f, 0.f, 0.f);
        if (gn < N) v = ((const float4*)(in_feat + (size_t)gn * IN_F))[k4];
        *(float4*)&Al[n][k4 * 4] = v;
    }
    __syncthreads();

    const int c4 = (t & 15) * 4;
    const int r4 = (t >> 4) * 4;
    float acc[4][4] = {};
#pragma unroll 4
    for (int k = 0; k < IN_F; k += 4) {
        float4 w0 = *(const float4*)&Wl[k + 0][c4];
        float4 w1 = *(const float4*)&Wl[k + 1][c4];
        float4 w2 = *(const float4*)&Wl[k + 2][c4];
        float4 w3 = *(const float4*)&Wl[k + 3][c4];
        const float* wp0 = (const float*)&w0;
        const float* wp1 = (const float*)&w1;
        const float* wp2 = (const float*)&w2;
        const float* wp3 = (const float*)&w3;
#pragma unroll
        for (int i = 0; i < 4; ++i) {
            float4 a = *(const float4*)&Al[r4 + i][k];
#pragma unroll
            for (int jj = 0; jj < 4; ++jj)
                acc[i][jj] = fmaf(a.x, wp0[jj],
                             fmaf(a.y, wp1[jj],
                             fmaf(a.z, wp2[jj],
                             fmaf(a.w, wp3[jj], acc[i][jj]))));
        }
    }
#pragma unroll
    for (int i = 0; i < 4; ++i) {
        int n = base + r4 + i;
        if (n < N) {
            float no = norm_out[n];
            int pk = 0;
            pk = __builtin_amdgcn_cvt_pk_fp8_f32(acc[i][0] * no, acc[i][1] * no, pk, false);
            pk = __builtin_amdgcn_cvt_pk_fp8_f32(acc[i][2] * no, acc[i][3] * no, pk, true);
            *(int*)&X1q[(size_t)n * H_F + c4] = pk;
        }
    }
}

// ---- aggregation: 64-node window, indices LDS-staged, register fp8 accumulation ------
// block = 64 nodes; wave w owns nodes [w*16, w*16+16); lane = feature.
__global__ __launch_bounds__(256) void k_agg(const unsigned char* __restrict__ X1q,
                                             const int* __restrict__ sortedSrc,
                                             const int* __restrict__ nodeOff,
                                             const float* __restrict__ norm_in,
                                             const float* __restrict__ norm_out,
                                             const float* __restrict__ wsum,
                                             const float* __restrict__ b1,
                                             float* __restrict__ partials, int N) {
    __shared__ int ids[CAP];          // 8 KB
    __shared__ int noff[AGG_W + 1];
    __shared__ float hl[4][64];
    const int tid = threadIdx.x, lane = tid & 63, wave = tid >> 6;
    const int gbase = blockIdx.x * AGG_W;
    const int nend = (gbase + AGG_W < N) ? gbase + AGG_W : N;
    const int nloc = nend - gbase;

    if (tid <= nloc) noff[tid] = nodeOff[gbase + tid];
    __syncthreads();
    const int s0 = noff[0];
    const int cnt = noff[nloc] - s0;
    const bool fast = (cnt <= CAP);
    if (fast) {
        for (int i = tid; i < cnt; i += 256) ids[i] = sortedSrc[s0 + i];
    }
    __syncthreads();

    const float bj = b1[lane];
    float hacc = 0.0f;
    for (int k = 0; k < 16; ++k) {
        int nl = wave * 16 + k;
        if (nl >= nloc) break;
        int gn = gbase + nl;
        int e0 = noff[nl] - s0, e1 = noff[nl + 1] - s0;
        float acc = 0.0f;
        int e = e0;
        if (fast) {
            for (; e + 7 < e1; e += 8) {
                int ss[8]; unsigned qq[8];
#pragma unroll
                for (int u = 0; u < 8; ++u) ss[u] = ids[e + u];
#pragma unroll
                for (int u = 0; u < 8; ++u) qq[u] = X1q[(size_t)ss[u] * H_F + lane];
#pragma unroll
                for (int u = 0; u < 8; ++u) acc += __builtin_amdgcn_cvt_f32_fp8(qq[u], 0);
            }
            for (; e < e1; ++e) {
                unsigned q = X1q[(size_t)ids[e] * H_F + lane];
                acc += __builtin_amdgcn_cvt_f32_fp8(q, 0);
            }
        } else {
            for (; e + 7 < e1; e += 8) {
                int ss[8]; unsigned qq[8];
#pragma unroll
                for (int u = 0; u < 8; ++u) ss[u] = sortedSrc[s0 + e + u];
#pragma unroll
                for (int u = 0; u < 8; ++u) qq[u] = X1q[(size_t)ss[u] * H_F + lane];
#pragma unroll
                for (int u = 0; u < 8; ++u) acc += __builtin_amdgcn_cvt_f32_fp8(qq[u], 0);
            }
            for (; e < e1; ++e) {
                unsigned q = X1q[(size_t)sortedSrc[s0 + e] * H_F + lane];
                acc += __builtin_amdgcn_cvt_f32_fp8(q, 0);
            }
        }
        float v = acc * norm_in[gn] + bj;
        hacc = fmaf(v > 0.0f ? v : 0.0f, norm_out[gn] * wsum[gn], hacc);
    }
    hl[wave][lane] = hacc;
    __syncthreads();
    if (wave == 0)
        partials[(size_t)blockIdx.x * 64 + lane] =
            (hl[0][lane] + hl[1][lane]) + (hl[2][lane] + hl[3][lane]);
}

// ---------------- stage-1 reduction: partials[nbp][64] -> red[NRED][64] (f64) ----------
__global__ __launch_bounds__(256) void k_red(const float* __restrict__ partials,
                                             double* __restrict__ red, int nbp) {
    const int lane = threadIdx.x & 63, wave = threadIdx.x >> 6;
    const int rpb = (nbp + NRED - 1) / NRED;
    const int r0 = blockIdx.x * rpb;
    int r1 = r0 + rpb; if (r1 > nbp) r1 = nbp;
    double s = 0.0;
    for (int r = r0 + wave; r < r1; r += 4)
        s += (double)partials[(size_t)r * 64 + lane];
    __shared__ double sd[4][64];
    sd[wave][lane] = s;
    __syncthreads();
    if (wave == 0)
        red[(size_t)blockIdx.x * 64 + lane] =
            (sd[0][lane] + sd[1][lane]) + (sd[2][lane] + sd[3][lane]);
}

// ---------------- final: red (f64) -> out = hsum@W2/N + b2 ----------------
__global__ __launch_bounds__(256) void k_final(const double* __restrict__ red,
                                               const float* __restrict__ W2,
                                               const float* __restrict__ b2,
                                               float* __restrict__ out, int N) {
    __shared__ double hs[4][64];
    const int sub = threadIdx.x >> 6;   // 0..3
    const int j   = threadIdx.x & 63;
    double s = 0.0;
    for (int p = sub; p < NRED; p += 4)
        s += red[(size_t)p * 64 + j];
    hs[sub][j] = s;
    __syncthreads();
    if (threadIdx.x < C_F) {
        int c = threadIdx.x;
        double o = 0.0;
        for (int k = 0; k < 64; ++k) {
            double hk = hs[0][k] + hs[1][k] + hs[2][k] + hs[3][k];
            o += hk * (double)W2[k * C_F + c];
        }
        out[c] = (float)(o / (double)N + (double)b2[c]);
    }
}

extern "C" void kernel_launch(void* const* d_in, const int* in_sizes, int n_in,
                              void* d_out, int out_size, void* d_ws, size_t ws_size,
                              hipStream_t stream) {
    const float* in_feat = (const float*)d_in[0];
    const int*   src     = (const int*)d_in[1];
    const int*   dst     = (const int*)d_in[2];
    const float* W1      = (const float*)d_in[3];
    const float* b1      = (const float*)d_in[4];
    const float* W2      = (const float*)d_in[5];
    const float* b2      = (const float*)d_in[6];
    float* out = (float*)d_out;

    const int N = in_sizes[0] / IN_F;           // 100000
    const int E = in_sizes[1];                  // 1600000
    const int nb = (N + BUCKET - 1) / BUCKET;   // 391 (<= MAXB)
    const int nBin = (E + EPB - 1) / EPB;       // 196
    const int nAgg = (N + AGG_W - 1) / AGG_W;   // 1563

    // ---- workspace layout (4B units) ----
    unsigned int* binnedD = (unsigned int*)d_ws;         // E
    unsigned int* binnedS = binnedD + E;                 // E
    int*   sortedSrc = (int*)(binnedS + E);              // E
    int*   cntD   = sortedSrc + E;                       // MAXB  \ zeroed
    int*   cntS   = cntD + MAXB;                         // MAXB  /
    int*   baseD  = cntS + MAXB;                         // MAXB+1
    int*   curD   = baseD + MAXB + 1;                    // MAXB
    int*   baseS  = curD + MAXB;                         // MAXB+1
    int*   curS   = baseS + MAXB + 1;                    // MAXB
    int*   nodeOff  = curS + MAXB;                       // N+1
    float* norm_in  = (float*)(nodeOff + N + 1);         // N
    float* norm_out = norm_in + N;                       // N
    float* wsum     = norm_out + N;                      // N
    unsigned char* X1q = (unsigned char*)(wsum + N);     // 64N bytes
    float* partials = (float*)(X1q + 64 * (size_t)N);    // nAgg*64
    double* red     = (double*)(partials + (size_t)nAgg * 64 + 64);  // NRED*64 (8B-align)

    // only the bucket-count accumulators are read-before-write
    hipMemsetAsync(cntD, 0, 2 * MAXB * sizeof(int), stream);

    k_bhist<<<nBin, 256, 0, stream>>>(src, dst, cntS, cntD, E, nb);

    k_bucketscan2<<<1, 1024, 0, stream>>>(cntD, cntS, baseD, curD, baseS, curS, nb, E);

    k_bin2<<<nBin, 256, 0, stream>>>(src, dst, curD, curS, binnedD, binnedS, E, nb);

    k_sortD<<<nb, 256, 0, stream>>>(binnedD, baseD, sortedSrc, nodeOff, norm_in, N, E);
    k_wsum <<<nb, 256, 0, stream>>>(binnedS, baseS, norm_in, wsum, norm_out, N);

    k_gemm1<<<(N + 63) / 64, 256, 0, stream>>>(in_feat, W1, norm_out, X1q, N);

    k_agg<<<nAgg, 256, 0, stream>>>(X1q, sortedSrc, nodeOff, norm_in, norm_out,
                                    wsum, b1, partials, N);

    k_red  <<<NRED, 256, 0, stream>>>(partials, red, nAgg);
    k_final<<<1, 256, 0, stream>>>(red, W2, b2, out, N);
}

// Round 15
// 199.869 us; speedup vs baseline: 1.2355x; 1.0016x over previous
//
#include <hip/hip_runtime.h>
#include <hip/hip_fp16.h>

#define IN_F 128
#define H_F 64
#define C_F 16
#define BUCKET 256          // nodes per bucket (binning granularity)
#define BSH 8               // log2(BUCKET)
#define MAXB 512            // hist/scan capacity (>= nBuckets = ceil(N/256))
#define EPB 8192            // edges per binning block
#define AGG_W 64            // nodes per k_agg block (window)
#define CAP 2048            // staged indices per k_agg block (8 KB)
#define NRED 64             // stage-1 reduction blocks
#define AK 136              // padded K (bf16) for MFMA tiles

typedef __attribute__((ext_vector_type(8))) short short8v;
typedef __attribute__((ext_vector_type(4))) float f32x4;

static __device__ inline short f2bf(float f) {   // fp32 -> bf16 bits, RNE
    unsigned u = __float_as_uint(f);
    unsigned r = (u + 0x7FFFu + ((u >> 16) & 1u)) >> 16;
    return (short)r;
}

// ---------------- fused bucket histograms (src + dst) ----------------
__global__ __launch_bounds__(256) void k_bhist(const int* __restrict__ src,
                                               const int* __restrict__ dst,
                                               int* __restrict__ cntS,
                                               int* __restrict__ cntD, int E, int nb) {
    __shared__ int hs[MAXB];
    __shared__ int hd[MAXB];
    const int tid = threadIdx.x;
    for (int i = tid; i < MAXB; i += 256) { hs[i] = 0; hd[i] = 0; }
    __syncthreads();
    const int start = blockIdx.x * EPB;
    for (int k = 0; k < EPB / 256; ++k) {
        int e = start + (k << 8) + tid;
        if (e < E) {
            atomicAdd(&hs[src[e] >> BSH], 1);
            atomicAdd(&hd[dst[e] >> BSH], 1);
        }
    }
    __syncthreads();
    for (int b = tid; b < nb; b += 256) {
        int s = hs[b], d = hd[b];
        if (s) atomicAdd(&cntS[b], s);
        if (d) atomicAdd(&cntD[b], d);
    }
}

// ------------- exclusive scans of BOTH bucket-count arrays (single block) -------------
__global__ __launch_bounds__(1024) void k_bucketscan2(const int* __restrict__ cntD,
                                                      const int* __restrict__ cntS,
                                                      int* __restrict__ baseD,
                                                      int* __restrict__ curD,
                                                      int* __restrict__ baseS,
                                                      int* __restrict__ curS,
                                                      int nb, int E) {
    __shared__ int s[1024];
    const int t = threadIdx.x;
    for (int pass = 0; pass < 2; ++pass) {
        const int* cnt = pass ? cntS : cntD;
        int* base = pass ? baseS : baseD;
        int* cur  = pass ? curS  : curD;
        int i0 = 2 * t, i1 = 2 * t + 1;
        int v0 = (i0 < nb) ? cnt[i0] : 0;
        int v1 = (i1 < nb) ? cnt[i1] : 0;
        int pair = v0 + v1;
        s[t] = pair;
        __syncthreads();
        for (int off = 1; off < 1024; off <<= 1) {
            int x = (t >= off) ? s[t - off] : 0;
            __syncthreads();
            s[t] += x;
            __syncthreads();
        }
        int excl = s[t] - pair;
        if (i0 < nb) { base[i0] = excl;      cur[i0] = excl; }
        if (i1 < nb) { base[i1] = excl + v0; cur[i1] = excl + v0; }
        if (t == 0) base[nb] = E;
        __syncthreads();
    }
}

// ------------- fused dual binning: by dst (pay=src) AND by src (pay=dst) --------------
__global__ __launch_bounds__(256) void k_bin2(const int* __restrict__ src,
                                              const int* __restrict__ dst,
                                              int* __restrict__ gCurD,
                                              int* __restrict__ gCurS,
                                              unsigned int* __restrict__ binnedD,
                                              unsigned int* __restrict__ binnedS,
                                              int E, int nb) {
    __shared__ int hd[MAXB], hs[MAXB];
    __shared__ int bd[MAXB], bs[MAXB];
    __shared__ int cd[MAXB], cs[MAXB];
    const int tid = threadIdx.x;
    const int start = blockIdx.x * EPB;
    for (int i = tid; i < MAXB; i += 256) { hd[i] = 0; hs[i] = 0; cd[i] = 0; cs[i] = 0; }
    __syncthreads();
    for (int k = 0; k < EPB / 256; ++k) {
        int e = start + (k << 8) + tid;
        if (e < E) {
            atomicAdd(&hd[dst[e] >> BSH], 1);
            atomicAdd(&hs[src[e] >> BSH], 1);
        }
    }
    __syncthreads();
    for (int b = tid; b < nb; b += 256) {
        if (hd[b]) bd[b] = atomicAdd(&gCurD[b], hd[b]);
        if (hs[b]) bs[b] = atomicAdd(&gCurS[b], hs[b]);
    }
    __syncthreads();
    for (int k = 0; k < EPB / 256; ++k) {
        int e = start + (k << 8) + tid;
        if (e < E) {
            int sv = src[e], dv = dst[e];
            int b1 = dv >> BSH;
            int p1 = bd[b1] + atomicAdd(&cd[b1], 1);
            binnedD[p1] = ((unsigned)(dv & (BUCKET - 1)) << 17) | (unsigned)sv;
            int b2 = sv >> BSH;
            int p2 = bs[b2] + atomicAdd(&cs[b2], 1);
            binnedS[p2] = ((unsigned)(sv & (BUCKET - 1)) << 17) | (unsigned)dv;
        }
    }
}

// ---- per-bucket counting sort of binnedD -> CSR (sortedSrc + nodeOff) + norm_in ------
__global__ __launch_bounds__(256) void k_sortD(const unsigned int* __restrict__ binnedD,
                                               const int* __restrict__ baseD,
                                               int* __restrict__ sortedSrc,
                                               int* __restrict__ nodeOff,
                                               float* __restrict__ norm_in,
                                               int N, int E) {
    __shared__ int hist[BUCKET];
    __shared__ int cur[BUCKET];
    __shared__ int wtot[4];
    const int tid = threadIdx.x, lane = tid & 63, wave = tid >> 6;
    const int b = blockIdx.x;
    const int s0 = baseD[b], s1 = baseD[b + 1];

    hist[tid] = 0;
    __syncthreads();
    for (int i = s0 + tid; i < s1; i += 256)
        atomicAdd(&hist[binnedD[i] >> 17], 1);
    __syncthreads();

    int v = hist[tid];
    int inc = v;
#pragma unroll
    for (int off = 1; off < 64; off <<= 1) {
        int t2 = __shfl_up(inc, off);
        if (lane >= off) inc += t2;
    }
    if (lane == 63) wtot[wave] = inc;
    __syncthreads();
    int add = 0;
#pragma unroll
    for (int w2 = 0; w2 < 4; ++w2)
        if (w2 < wave) add += wtot[w2];
    int excl = add + inc - v;
    cur[tid] = s0 + excl;
    int gn = b * BUCKET + tid;
    if (gn < N) {
        nodeOff[gn] = s0 + excl;
        norm_in[gn] = 1.0f / sqrtf((float)max(v, 1));
        if (gn == N - 1) nodeOff[N] = E;
    }
    __syncthreads();

    for (int i = s0 + tid; i < s1; i += 256) {
        unsigned c = binnedD[i];
        int p = atomicAdd(&cur[c >> 17], 1);
        sortedSrc[p] = (int)(c & 0x1FFFFu);
    }
}

// ---------------- wsum + norm_out from binnedS (per src-bucket) ----------------
__global__ __launch_bounds__(256) void k_wsum(const unsigned int* __restrict__ binnedS,
                                              const int* __restrict__ baseS,
                                              const float* __restrict__ norm_in,
                                              float* __restrict__ wsum,
                                              float* __restrict__ norm_out, int N) {
    __shared__ float wloc[BUCKET];
    __shared__ int hist[BUCKET];
    const int tid = threadIdx.x;
    wloc[tid] = 0.0f;
    hist[tid] = 0;
    __syncthreads();
    const int b = blockIdx.x;
    const int s0 = baseS[b], s1 = baseS[b + 1];
    for (int i = s0 + tid; i < s1; i += 256) {
        unsigned c = binnedS[i];
        int sl = (int)(c >> 17);
        float ni = norm_in[c & 0x1FFFFu];
        atomicAdd(&hist[sl], 1);
        atomicAdd(&wloc[sl], ni);
    }
    __syncthreads();
    int gn = b * BUCKET + tid;
    if (gn < N) {
        norm_out[gn] = 1.0f / sqrtf((float)max(hist[tid], 1));
        wsum[gn] = wloc[tid];
    }
}

// ------- layer 1 GEMM via bf16 MFMA: X1q{A,B} = fp8((in_feat @ W1) * norm_out) -------
// 64 nodes/block, 4 waves. A-tile & W^T in bf16 LDS; C f32 tile aliases A.
__global__ __launch_bounds__(256) void k_gemm1(const float* __restrict__ in_feat,
                                               const float* __restrict__ W1,
                                               const float* __restrict__ norm_out,
                                               unsigned char* __restrict__ X1qA,
                                               unsigned char* __restrict__ X1qB, int N) {
    __shared__ union {
        short a[64][AK];     // bf16 A-tile [node][k], 17408 B
        float c[64][68];     // f32 C-tile [node][col], 17408 B
    } u;
    __shared__ short wt[64][AK];   // bf16 W^T [col][k], 17408 B
    const int t = threadIdx.x;
    const int lane = t & 63, wave = t >> 6;
    const int base = blockIdx.x * 64;

    // stage W^T (transposed, bf16)
    for (int i = t; i < IN_F * H_F; i += 256) {
        int k = i >> 6, n = i & 63;
        wt[n][k] = f2bf(W1[i]);
    }
    // stage A-tile (bf16)
    for (int i = t; i < 64 * IN_F / 4; i += 256) {
        int n = i >> 5, k4 = (i & 31) * 4;
        int gn = base + n;
        float4 v = make_float4(0.f, 0.f, 0.f, 0.f);
        if (gn < N) v = *(const float4*)(in_feat + (size_t)gn * IN_F + k4);
        short4 s4 = make_short4(f2bf(v.x), f2bf(v.y), f2bf(v.z), f2bf(v.w));
        *(short4*)&u.a[n][k4] = s4;
    }
    __syncthreads();

    // MFMA: wave w -> rows 16w..16w+15; 4 col-blocks x 4 k-blocks
    f32x4 acc0 = {}, acc1 = {}, acc2 = {}, acc3 = {};
    const int rowb = wave * 16 + (lane & 15);
    const int ko = (lane >> 4) * 8;
#pragma unroll
    for (int kk = 0; kk < 4; ++kk) {
        short8v af = *(const short8v*)&u.a[rowb][kk * 32 + ko];
        short8v b0 = *(const short8v*)&wt[0 + (lane & 15)][kk * 32 + ko];
        short8v b1f = *(const short8v*)&wt[16 + (lane & 15)][kk * 32 + ko];
        short8v b2 = *(const short8v*)&wt[32 + (lane & 15)][kk * 32 + ko];
        short8v b3 = *(const short8v*)&wt[48 + (lane & 15)][kk * 32 + ko];
        acc0 = __builtin_amdgcn_mfma_f32_16x16x32_bf16(af, b0, acc0, 0, 0, 0);
        acc1 = __builtin_amdgcn_mfma_f32_16x16x32_bf16(af, b1f, acc1, 0, 0, 0);
        acc2 = __builtin_amdgcn_mfma_f32_16x16x32_bf16(af, b2, acc2, 0, 0, 0);
        acc3 = __builtin_amdgcn_mfma_f32_16x16x32_bf16(af, b3, acc3, 0, 0, 0);
    }
    __syncthreads();   // done reading A-tile; reuse as C-tile

    // C layout: col = lane&15 (+16*nb), row = 16*wave + (lane>>4)*4 + r
    {
        const int col = lane & 15;
        const int row0 = wave * 16 + (lane >> 4) * 4;
#pragma unroll
        for (int r = 0; r < 4; ++r) {
            u.c[row0 + r][col +  0] = acc0[r];
            u.c[row0 + r][col + 16] = acc1[r];
            u.c[row0 + r][col + 32] = acc2[r];
            u.c[row0 + r][col + 48] = acc3[r];
        }
    }
    __syncthreads();

    // epilogue: thread t -> node t>>2, feature quad (t&3)*16; fp8 pack, split-half write
    {
        int n = t >> 2, fq = (t & 3) * 16;
        int gn = base + n;
        if (gn < N) {
            float no = norm_out[gn];
            unsigned pk[4];
#pragma unroll
            for (int q = 0; q < 4; ++q) {
                int f = fq + q * 4;
                int w0 = 0;
                w0 = __builtin_amdgcn_cvt_pk_fp8_f32(u.c[n][f + 0] * no, u.c[n][f + 1] * no, w0, false);
                w0 = __builtin_amdgcn_cvt_pk_fp8_f32(u.c[n][f + 2] * no, u.c[n][f + 3] * no, w0, true);
                pk[q] = (unsigned)w0;
            }
            uint4 o = make_uint4(pk[0], pk[1], pk[2], pk[3]);
            unsigned char* dst = (t & 2) ? X1qB : X1qA;
            int fo = (t & 1) * 16;
            *(uint4*)&dst[(size_t)gn * 32 + fo] = o;
        }
    }
}

// ---- aggregation: 64-node window, feature-half split (L2-resident 3.2MB gathers) -----
// blockIdx.y = half. Wave: lane = (edge_parity<<5) | feat; 2 edges/instr, 32B rows.
__global__ __launch_bounds__(256) void k_agg(const unsigned char* __restrict__ X1qA,
                                             const unsigned char* __restrict__ X1qB,
                                             const int* __restrict__ sortedSrc,
                                             const int* __restrict__ nodeOff,
                                             const float* __restrict__ norm_in,
                                             const float* __restrict__ norm_out,
                                             const float* __restrict__ wsum,
                                             const float* __restrict__ b1,
                                             float* __restrict__ partials, int N) {
    __shared__ int ids[CAP];
    __shared__ int noff[AGG_W + 1];
    __shared__ float hl[4][32];
    const int tid = threadIdx.x, lane = tid & 63, wave = tid >> 6;
    const int half = blockIdx.y;
    const unsigned char* __restrict__ Xh = half ? X1qB : X1qA;
    const int fb = lane & 31;
    const int eo = lane >> 5;           // 0 or 1
    const int gbase = blockIdx.x * AGG_W;
    const int nend = (gbase + AGG_W < N) ? gbase + AGG_W : N;
    const int nloc = nend - gbase;

    if (tid <= nloc) noff[tid] = nodeOff[gbase + tid];
    __syncthreads();
    const int s0 = noff[0];
    const int cnt = noff[nloc] - s0;
    const bool fast = (cnt <= CAP);
    if (fast) {
        for (int i = tid; i < cnt; i += 256) ids[i] = sortedSrc[s0 + i];
    }
    __syncthreads();

    const float bj = b1[half * 32 + fb];
    float hacc = 0.0f;
    for (int k = 0; k < 16; ++k) {
        int nl = wave * 16 + k;
        if (nl >= nloc) break;
        int gn = gbase + nl;
        int e0 = noff[nl] - s0, e1 = noff[nl + 1] - s0;
        float acc = 0.0f;
        int e = e0 + eo;
        if (fast) {
            for (; e + 14 < e1; e += 16) {
                int ss[8]; unsigned qq[8];
#pragma unroll
                for (int uu = 0; uu < 8; ++uu) ss[uu] = ids[e + 2 * uu];
#pragma unroll
                for (int uu = 0; uu < 8; ++uu) qq[uu] = Xh[(size_t)ss[uu] * 32 + fb];
#pragma unroll
                for (int uu = 0; uu < 8; ++uu) acc += __builtin_amdgcn_cvt_f32_fp8(qq[uu], 0);
            }
            for (; e < e1; e += 2) {
                unsigned q = Xh[(size_t)ids[e] * 32 + fb];
                acc += __builtin_amdgcn_cvt_f32_fp8(q, 0);
            }
        } else {
            for (; e < e1; e += 2) {
                unsigned q = Xh[(size_t)sortedSrc[s0 + e] * 32 + fb];
                acc += __builtin_amdgcn_cvt_f32_fp8(q, 0);
            }
        }
        acc += __shfl_xor(acc, 32);
        float v = acc * norm_in[gn] + bj;
        hacc = fmaf(v > 0.0f ? v : 0.0f, norm_out[gn] * wsum[gn], hacc);
    }
    if (lane < 32) hl[wave][lane] = hacc;
    __syncthreads();
    if (tid < 32)
        partials[(size_t)blockIdx.x * 64 + half * 32 + tid] =
            (hl[0][tid] + hl[1][tid]) + (hl[2][tid] + hl[3][tid]);
}

// ---------------- stage-1 reduction: partials[nbp][64] -> red[NRED][64] (f64) ----------
__global__ __launch_bounds__(256) void k_red(const float* __restrict__ partials,
                                             double* __restrict__ red, int nbp) {
    const int lane = threadIdx.x & 63, wave = threadIdx.x >> 6;
    const int rpb = (nbp + NRED - 1) / NRED;
    const int r0 = blockIdx.x * rpb;
    int r1 = r0 + rpb; if (r1 > nbp) r1 = nbp;
    double s = 0.0;
    for (int r = r0 + wave; r < r1; r += 4)
        s += (double)partials[(size_t)r * 64 + lane];
    __shared__ double sd[4][64];
    sd[wave][lane] = s;
    __syncthreads();
    if (wave == 0)
        red[(size_t)blockIdx.x * 64 + lane] =
            (sd[0][lane] + sd[1][lane]) + (sd[2][lane] + sd[3][lane]);
}

// ---------------- final: red (f64) -> out = hsum@W2/N + b2 ----------------
__global__ __launch_bounds__(256) void k_final(const double* __restrict__ red,
                                               const float* __restrict__ W2,
                                               const float* __restrict__ b2,
                                               float* __restrict__ out, int N) {
    __shared__ double hs[4][64];
    const int sub = threadIdx.x >> 6;
    const int j   = threadIdx.x & 63;
    double s = 0.0;
    for (int p = sub; p < NRED; p += 4)
        s += red[(size_t)p * 64 + j];
    hs[sub][j] = s;
    __syncthreads();
    if (threadIdx.x < C_F) {
        int c = threadIdx.x;
        double o = 0.0;
        for (int k = 0; k < 64; ++k) {
            double hk = hs[0][k] + hs[1][k] + hs[2][k] + hs[3][k];
            o += hk * (double)W2[k * C_F + c];
        }
        out[c] = (float)(o / (double)N + (double)b2[c]);
    }
}

extern "C" void kernel_launch(void* const* d_in, const int* in_sizes, int n_in,
                              void* d_out, int out_size, void* d_ws, size_t ws_size,
                              hipStream_t stream) {
    const float* in_feat = (const float*)d_in[0];
    const int*   src     = (const int*)d_in[1];
    const int*   dst     = (const int*)d_in[2];
    const float* W1      = (const float*)d_in[3];
    const float* b1      = (const float*)d_in[4];
    const float* W2      = (const float*)d_in[5];
    const float* b2      = (const float*)d_in[6];
    float* out = (float*)d_out;

    const int N = in_sizes[0] / IN_F;           // 100000
    const int E = in_sizes[1];                  // 1600000
    const int nb = (N + BUCKET - 1) / BUCKET;   // 391
    const int nBin = (E + EPB - 1) / EPB;       // 196
    const int nAgg = (N + AGG_W - 1) / AGG_W;   // 1563

    // ---- workspace layout with explicit alignment ----
    char* p = (char*)d_ws;
    auto alloc = [&](size_t bytes, size_t align) -> void* {
        size_t a = ((size_t)p + align - 1) & ~(align - 1);
        p = (char*)(a + bytes);
        return (void*)a;
    };
    unsigned char* X1qA = (unsigned char*)alloc(32 * (size_t)N, 16);
    unsigned char* X1qB = (unsigned char*)alloc(32 * (size_t)N, 16);
    unsigned int* binnedD = (unsigned int*)alloc(4 * (size_t)E, 16);
    unsigned int* binnedS = (unsigned int*)alloc(4 * (size_t)E, 16);
    int*   sortedSrc = (int*)alloc(4 * (size_t)E, 16);
    int*   cntD   = (int*)alloc(4 * MAXB, 16);          // \ zeroed together
    int*   cntS   = (int*)alloc(4 * MAXB, 4);           // /
    int*   baseD  = (int*)alloc(4 * (MAXB + 1), 4);
    int*   curD   = (int*)alloc(4 * MAXB, 4);
    int*   baseS  = (int*)alloc(4 * (MAXB + 1), 4);
    int*   curS   = (int*)alloc(4 * MAXB, 4);
    int*   nodeOff  = (int*)alloc(4 * ((size_t)N + 1), 4);
    float* norm_in  = (float*)alloc(4 * (size_t)N, 4);
    float* norm_out = (float*)alloc(4 * (size_t)N, 4);
    float* wsum     = (float*)alloc(4 * (size_t)N, 4);
    float* partials = (float*)alloc(4 * (size_t)nAgg * 64, 16);
    double* red     = (double*)alloc(8 * (size_t)NRED * 64, 8);

    // only the bucket-count accumulators are read-before-write
    hipMemsetAsync(cntD, 0, 2 * MAXB * sizeof(int), stream);

    k_bhist<<<nBin, 256, 0, stream>>>(src, dst, cntS, cntD, E, nb);

    k_bucketscan2<<<1, 1024, 0, stream>>>(cntD, cntS, baseD, curD, baseS, curS, nb, E);

    k_bin2<<<nBin, 256, 0, stream>>>(src, dst, curD, curS, binnedD, binnedS, E, nb);

    k_sortD<<<nb, 256, 0, stream>>>(binnedD, baseD, sortedSrc, nodeOff, norm_in, N, E);
    k_wsum <<<nb, 256, 0, stream>>>(binnedS, baseS, norm_in, wsum, norm_out, N);

    k_gemm1<<<(N + 63) / 64, 256, 0, stream>>>(in_feat, W1, norm_out, X1qA, X1qB, N);

    dim3 gAgg(nAgg, 2);
    k_agg<<<gAgg, 256, 0, stream>>>(X1qA, X1qB, sortedSrc, nodeOff, norm_in, norm_out,
                                    wsum, b1, partials, N);

    k_red  <<<NRED, 256, 0, stream>>>(partials, red, nAgg);
    k_final<<<1, 256, 0, stream>>>(red, W2, b2, out, N);
}

// Round 16
// 162.024 us; speedup vs baseline: 1.5241x; 1.2336x over previous
//
#include <hip/hip_runtime.h>
#include <hip/hip_fp16.h>

#define IN_F 128
#define H_F 64
#define C_F 16
#define BUCKET 256          // nodes per bucket (binning granularity)
#define BSH 8               // log2(BUCKET)
#define MAXB 512            // hist/scan capacity (>= nBuckets = ceil(N/256))
#define EPB 8192            // edges per binning block
#define AGG_W 64            // nodes per k_agg block (window)
#define CAP 2048            // staged indices per k_agg block (8 KB)
#define NRED 64             // stage-1 reduction blocks
#define AK 136              // padded K (bf16) for MFMA tiles

typedef __attribute__((ext_vector_type(8))) short short8v;
typedef __attribute__((ext_vector_type(4))) float f32x4;

static __device__ inline short f2bf(float f) {   // fp32 -> bf16 bits, RNE
    unsigned u = __float_as_uint(f);
    unsigned r = (u + 0x7FFFu + ((u >> 16) & 1u)) >> 16;
    return (short)r;
}

// ---------------- fused bucket histograms (src + dst) ----------------
__global__ __launch_bounds__(256) void k_bhist(const int* __restrict__ src,
                                               const int* __restrict__ dst,
                                               int* __restrict__ cntS,
                                               int* __restrict__ cntD, int E, int nb) {
    __shared__ int hs[MAXB];
    __shared__ int hd[MAXB];
    const int tid = threadIdx.x;
    for (int i = tid; i < MAXB; i += 256) { hs[i] = 0; hd[i] = 0; }
    __syncthreads();
    const int start = blockIdx.x * EPB;
    for (int k = 0; k < EPB / 256; ++k) {
        int e = start + (k << 8) + tid;
        if (e < E) {
            atomicAdd(&hs[src[e] >> BSH], 1);
            atomicAdd(&hd[dst[e] >> BSH], 1);
        }
    }
    __syncthreads();
    for (int b = tid; b < nb; b += 256) {
        int s = hs[b], d = hd[b];
        if (s) atomicAdd(&cntS[b], s);
        if (d) atomicAdd(&cntD[b], d);
    }
}

// ------------- exclusive scans of BOTH bucket-count arrays (single block) -------------
__global__ __launch_bounds__(1024) void k_bucketscan2(const int* __restrict__ cntD,
                                                      const int* __restrict__ cntS,
                                                      int* __restrict__ baseD,
                                                      int* __restrict__ curD,
                                                      int* __restrict__ baseS,
                                                      int* __restrict__ curS,
                                                      int nb, int E) {
    __shared__ int s[1024];
    const int t = threadIdx.x;
    for (int pass = 0; pass < 2; ++pass) {
        const int* cnt = pass ? cntS : cntD;
        int* base = pass ? baseS : baseD;
        int* cur  = pass ? curS  : curD;
        int i0 = 2 * t, i1 = 2 * t + 1;
        int v0 = (i0 < nb) ? cnt[i0] : 0;
        int v1 = (i1 < nb) ? cnt[i1] : 0;
        int pair = v0 + v1;
        s[t] = pair;
        __syncthreads();
        for (int off = 1; off < 1024; off <<= 1) {
            int x = (t >= off) ? s[t - off] : 0;
            __syncthreads();
            s[t] += x;
            __syncthreads();
        }
        int excl = s[t] - pair;
        if (i0 < nb) { base[i0] = excl;      cur[i0] = excl; }
        if (i1 < nb) { base[i1] = excl + v0; cur[i1] = excl + v0; }
        if (t == 0) base[nb] = E;
        __syncthreads();
    }
}

// ------------- fused dual binning: by dst (pay=src) AND by src (pay=dst) --------------
__global__ __launch_bounds__(256) void k_bin2(const int* __restrict__ src,
                                              const int* __restrict__ dst,
                                              int* __restrict__ gCurD,
                                              int* __restrict__ gCurS,
                                              unsigned int* __restrict__ binnedD,
                                              unsigned int* __restrict__ binnedS,
                                              int E, int nb) {
    __shared__ int hd[MAXB], hs[MAXB];
    __shared__ int bd[MAXB], bs[MAXB];
    __shared__ int cd[MAXB], cs[MAXB];
    const int tid = threadIdx.x;
    const int start = blockIdx.x * EPB;
    for (int i = tid; i < MAXB; i += 256) { hd[i] = 0; hs[i] = 0; cd[i] = 0; cs[i] = 0; }
    __syncthreads();
    for (int k = 0; k < EPB / 256; ++k) {
        int e = start + (k << 8) + tid;
        if (e < E) {
            atomicAdd(&hd[dst[e] >> BSH], 1);
            atomicAdd(&hs[src[e] >> BSH], 1);
        }
    }
    __syncthreads();
    for (int b = tid; b < nb; b += 256) {
        if (hd[b]) bd[b] = atomicAdd(&gCurD[b], hd[b]);
        if (hs[b]) bs[b] = atomicAdd(&gCurS[b], hs[b]);
    }
    __syncthreads();
    for (int k = 0; k < EPB / 256; ++k) {
        int e = start + (k << 8) + tid;
        if (e < E) {
            int sv = src[e], dv = dst[e];
            int b1 = dv >> BSH;
            int p1 = bd[b1] + atomicAdd(&cd[b1], 1);
            binnedD[p1] = ((unsigned)(dv & (BUCKET - 1)) << 17) | (unsigned)sv;
            int b2 = sv >> BSH;
            int p2 = bs[b2] + atomicAdd(&cs[b2], 1);
            binnedS[p2] = ((unsigned)(sv & (BUCKET - 1)) << 17) | (unsigned)dv;
        }
    }
}

// ---- per-bucket counting sort of binnedD -> CSR (sortedSrc + nodeOff) + norm_in ------
__global__ __launch_bounds__(256) void k_sortD(const unsigned int* __restrict__ binnedD,
                                               const int* __restrict__ baseD,
                                               int* __restrict__ sortedSrc,
                                               int* __restrict__ nodeOff,
                                               float* __restrict__ norm_in,
                                               int N, int E) {
    __shared__ int hist[BUCKET];
    __shared__ int cur[BUCKET];
    __shared__ int wtot[4];
    const int tid = threadIdx.x, lane = tid & 63, wave = tid >> 6;
    const int b = blockIdx.x;
    const int s0 = baseD[b], s1 = baseD[b + 1];

    hist[tid] = 0;
    __syncthreads();
    for (int i = s0 + tid; i < s1; i += 256)
        atomicAdd(&hist[binnedD[i] >> 17], 1);
    __syncthreads();

    int v = hist[tid];
    int inc = v;
#pragma unroll
    for (int off = 1; off < 64; off <<= 1) {
        int t2 = __shfl_up(inc, off);
        if (lane >= off) inc += t2;
    }
    if (lane == 63) wtot[wave] = inc;
    __syncthreads();
    int add = 0;
#pragma unroll
    for (int w2 = 0; w2 < 4; ++w2)
        if (w2 < wave) add += wtot[w2];
    int excl = add + inc - v;
    cur[tid] = s0 + excl;
    int gn = b * BUCKET + tid;
    if (gn < N) {
        nodeOff[gn] = s0 + excl;
        norm_in[gn] = 1.0f / sqrtf((float)max(v, 1));
        if (gn == N - 1) nodeOff[N] = E;
    }
    __syncthreads();

    for (int i = s0 + tid; i < s1; i += 256) {
        unsigned c = binnedD[i];
        int p = atomicAdd(&cur[c >> 17], 1);
        sortedSrc[p] = (int)(c & 0x1FFFFu);
    }
}

// ---------------- wsum + norm_out from binnedS (per src-bucket) ----------------
__global__ __launch_bounds__(256) void k_wsum(const unsigned int* __restrict__ binnedS,
                                              const int* __restrict__ baseS,
                                              const float* __restrict__ norm_in,
                                              float* __restrict__ wsum,
                                              float* __restrict__ norm_out, int N) {
    __shared__ float wloc[BUCKET];
    __shared__ int hist[BUCKET];
    const int tid = threadIdx.x;
    wloc[tid] = 0.0f;
    hist[tid] = 0;
    __syncthreads();
    const int b = blockIdx.x;
    const int s0 = baseS[b], s1 = baseS[b + 1];
    for (int i = s0 + tid; i < s1; i += 256) {
        unsigned c = binnedS[i];
        int sl = (int)(c >> 17);
        float ni = norm_in[c & 0x1FFFFu];
        atomicAdd(&hist[sl], 1);
        atomicAdd(&wloc[sl], ni);
    }
    __syncthreads();
    int gn = b * BUCKET + tid;
    if (gn < N) {
        norm_out[gn] = 1.0f / sqrtf((float)max(hist[tid], 1));
        wsum[gn] = wloc[tid];
    }
}

// ------- layer 1 GEMM via bf16 MFMA: X1q = fp8((in_feat @ W1) * norm_out), [N][64] ----
__global__ __launch_bounds__(256) void k_gemm1(const float* __restrict__ in_feat,
                                               const float* __restrict__ W1,
                                               const float* __restrict__ norm_out,
                                               unsigned char* __restrict__ X1q, int N) {
    __shared__ union {
        short a[64][AK];     // bf16 A-tile [node][k]
        float c[64][68];     // f32 C-tile [node][col]
    } u;
    __shared__ short wt[64][AK];   // bf16 W^T [col][k]
    const int t = threadIdx.x;
    const int lane = t & 63, wave = t >> 6;
    const int base = blockIdx.x * 64;

    for (int i = t; i < IN_F * H_F; i += 256) {
        int k = i >> 6, n = i & 63;
        wt[n][k] = f2bf(W1[i]);
    }
    for (int i = t; i < 64 * IN_F / 4; i += 256) {
        int n = i >> 5, k4 = (i & 31) * 4;
        int gn = base + n;
        float4 v = make_float4(0.f, 0.f, 0.f, 0.f);
        if (gn < N) v = *(const float4*)(in_feat + (size_t)gn * IN_F + k4);
        short4 s4 = make_short4(f2bf(v.x), f2bf(v.y), f2bf(v.z), f2bf(v.w));
        *(short4*)&u.a[n][k4] = s4;
    }
    __syncthreads();

    f32x4 acc0 = {}, acc1 = {}, acc2 = {}, acc3 = {};
    const int rowb = wave * 16 + (lane & 15);
    const int ko = (lane >> 4) * 8;
#pragma unroll
    for (int kk = 0; kk < 4; ++kk) {
        short8v af = *(const short8v*)&u.a[rowb][kk * 32 + ko];
        short8v b0 = *(const short8v*)&wt[0 + (lane & 15)][kk * 32 + ko];
        short8v b1f = *(const short8v*)&wt[16 + (lane & 15)][kk * 32 + ko];
        short8v b2 = *(const short8v*)&wt[32 + (lane & 15)][kk * 32 + ko];
        short8v b3 = *(const short8v*)&wt[48 + (lane & 15)][kk * 32 + ko];
        acc0 = __builtin_amdgcn_mfma_f32_16x16x32_bf16(af, b0, acc0, 0, 0, 0);
        acc1 = __builtin_amdgcn_mfma_f32_16x16x32_bf16(af, b1f, acc1, 0, 0, 0);
        acc2 = __builtin_amdgcn_mfma_f32_16x16x32_bf16(af, b2, acc2, 0, 0, 0);
        acc3 = __builtin_amdgcn_mfma_f32_16x16x32_bf16(af, b3, acc3, 0, 0, 0);
    }
    __syncthreads();   // done reading A-tile; reuse as C-tile

    {
        const int col = lane & 15;
        const int row0 = wave * 16 + (lane >> 4) * 4;
#pragma unroll
        for (int r = 0; r < 4; ++r) {
            u.c[row0 + r][col +  0] = acc0[r];
            u.c[row0 + r][col + 16] = acc1[r];
            u.c[row0 + r][col + 32] = acc2[r];
            u.c[row0 + r][col + 48] = acc3[r];
        }
    }
    __syncthreads();

    {
        int n = t >> 2, fq = (t & 3) * 16;
        int gn = base + n;
        if (gn < N) {
            float no = norm_out[gn];
            unsigned pk[4];
#pragma unroll
            for (int q = 0; q < 4; ++q) {
                int f = fq + q * 4;
                int w0 = 0;
                w0 = __builtin_amdgcn_cvt_pk_fp8_f32(u.c[n][f + 0] * no, u.c[n][f + 1] * no, w0, false);
                w0 = __builtin_amdgcn_cvt_pk_fp8_f32(u.c[n][f + 2] * no, u.c[n][f + 3] * no, w0, true);
                pk[q] = (unsigned)w0;
            }
            *(uint4*)&X1q[(size_t)gn * 64 + fq] = make_uint4(pk[0], pk[1], pk[2], pk[3]);
        }
    }
}

// ---- aggregation: 64-node window; lane = (edge_sub:2 | feat_quad:4); 256B/gather-instr
__global__ __launch_bounds__(256) void k_agg(const unsigned char* __restrict__ X1q,
                                             const int* __restrict__ sortedSrc,
                                             const int* __restrict__ nodeOff,
                                             const float* __restrict__ norm_in,
                                             const float* __restrict__ norm_out,
                                             const float* __restrict__ wsum,
                                             const float* __restrict__ b1,
                                             float* __restrict__ partials, int N) {
    __shared__ int ids[CAP];
    __shared__ int noff[AGG_W + 1];
    __shared__ float hl[4][64];
    const int tid = threadIdx.x, lane = tid & 63, wave = tid >> 6;
    const int fq = (lane & 15) * 4;   // feature quad base
    const int eo = lane >> 4;         // edge subgroup 0..3
    const int gbase = blockIdx.x * AGG_W;
    const int nend = (gbase + AGG_W < N) ? gbase + AGG_W : N;
    const int nloc = nend - gbase;

    if (tid <= nloc) noff[tid] = nodeOff[gbase + tid];
    __syncthreads();
    const int s0 = noff[0];
    const int cnt = noff[nloc] - s0;
    const bool fast = (cnt <= CAP);
    if (fast) {
        for (int i = tid; i < cnt; i += 256) ids[i] = sortedSrc[s0 + i];
    }
    __syncthreads();

    const float bj0 = b1[fq + 0], bj1 = b1[fq + 1];
    const float bj2 = b1[fq + 2], bj3 = b1[fq + 3];
    float h0 = 0.f, h1 = 0.f, h2 = 0.f, h3 = 0.f;

    for (int k = 0; k < 16; ++k) {
        int nl = wave * 16 + k;
        if (nl >= nloc) break;
        int gn = gbase + nl;
        int e0 = noff[nl] - s0, e1 = noff[nl + 1] - s0;
        float a0 = 0.f, a1 = 0.f, a2 = 0.f, a3 = 0.f;
        for (int e = e0; e < e1; e += 16) {   // 4 subgroups x 4-deep = 16 edges/iter
            int sv[4];
            unsigned qv[4];
#pragma unroll
            for (int u = 0; u < 4; ++u) {
                int ee = e + 4 * u + eo;
                sv[u] = (ee < e1) ? (fast ? ids[ee] : sortedSrc[s0 + ee]) : -1;
            }
#pragma unroll
            for (int u = 0; u < 4; ++u)
                qv[u] = (sv[u] >= 0) ? *(const unsigned*)&X1q[(size_t)sv[u] * 64 + fq] : 0u;
#pragma unroll
            for (int u = 0; u < 4; ++u) {
                a0 += __builtin_amdgcn_cvt_f32_fp8(qv[u], 0);
                a1 += __builtin_amdgcn_cvt_f32_fp8(qv[u], 1);
                a2 += __builtin_amdgcn_cvt_f32_fp8(qv[u], 2);
                a3 += __builtin_amdgcn_cvt_f32_fp8(qv[u], 3);
            }
        }
        // merge the 4 edge subgroups (lanes differing in bits 4-5)
        a0 += __shfl_xor(a0, 16); a0 += __shfl_xor(a0, 32);
        a1 += __shfl_xor(a1, 16); a1 += __shfl_xor(a1, 32);
        a2 += __shfl_xor(a2, 16); a2 += __shfl_xor(a2, 32);
        a3 += __shfl_xor(a3, 16); a3 += __shfl_xor(a3, 32);
        float ni = norm_in[gn];
        float w  = norm_out[gn] * wsum[gn];
        float v0 = a0 * ni + bj0, v1 = a1 * ni + bj1;
        float v2 = a2 * ni + bj2, v3 = a3 * ni + bj3;
        h0 = fmaf(v0 > 0.f ? v0 : 0.f, w, h0);
        h1 = fmaf(v1 > 0.f ? v1 : 0.f, w, h1);
        h2 = fmaf(v2 > 0.f ? v2 : 0.f, w, h2);
        h3 = fmaf(v3 > 0.f ? v3 : 0.f, w, h3);
    }
    if (lane < 16) {
        hl[wave][fq + 0] = h0; hl[wave][fq + 1] = h1;
        hl[wave][fq + 2] = h2; hl[wave][fq + 3] = h3;
    }
    __syncthreads();
    if (wave == 0)
        partials[(size_t)blockIdx.x * 64 + lane] =
            (hl[0][lane] + hl[1][lane]) + (hl[2][lane] + hl[3][lane]);
}

// ---------------- stage-1 reduction: partials[nbp][64] -> red[NRED][64] (f64) ----------
__global__ __launch_bounds__(256) void k_red(const float* __restrict__ partials,
                                             double* __restrict__ red, int nbp) {
    const int lane = threadIdx.x & 63, wave = threadIdx.x >> 6;
    const int rpb = (nbp + NRED - 1) / NRED;
    const int r0 = blockIdx.x * rpb;
    int r1 = r0 + rpb; if (r1 > nbp) r1 = nbp;
    double s = 0.0;
    for (int r = r0 + wave; r < r1; r += 4)
        s += (double)partials[(size_t)r * 64 + lane];
    __shared__ double sd[4][64];
    sd[wave][lane] = s;
    __syncthreads();
    if (wave == 0)
        red[(size_t)blockIdx.x * 64 + lane] =
            (sd[0][lane] + sd[1][lane]) + (sd[2][lane] + sd[3][lane]);
}

// ---------------- final: red (f64) -> out = hsum@W2/N + b2 ----------------
__global__ __launch_bounds__(256) void k_final(const double* __restrict__ red,
                                               const float* __restrict__ W2,
                                               const float* __restrict__ b2,
                                               float* __restrict__ out, int N) {
    __shared__ double hs[4][64];
    const int sub = threadIdx.x >> 6;
    const int j   = threadIdx.x & 63;
    double s = 0.0;
    for (int p = sub; p < NRED; p += 4)
        s += red[(size_t)p * 64 + j];
    hs[sub][j] = s;
    __syncthreads();
    if (threadIdx.x < C_F) {
        int c = threadIdx.x;
        double o = 0.0;
        for (int k = 0; k < 64; ++k) {
            double hk = hs[0][k] + hs[1][k] + hs[2][k] + hs[3][k];
            o += hk * (double)W2[k * C_F + c];
        }
        out[c] = (float)(o / (double)N + (double)b2[c]);
    }
}

extern "C" void kernel_launch(void* const* d_in, const int* in_sizes, int n_in,
                              void* d_out, int out_size, void* d_ws, size_t ws_size,
                              hipStream_t stream) {
    const float* in_feat = (const float*)d_in[0];
    const int*   src     = (const int*)d_in[1];
    const int*   dst     = (const int*)d_in[2];
    const float* W1      = (const float*)d_in[3];
    const float* b1      = (const float*)d_in[4];
    const float* W2      = (const float*)d_in[5];
    const float* b2      = (const float*)d_in[6];
    float* out = (float*)d_out;

    const int N = in_sizes[0] / IN_F;           // 100000
    const int E = in_sizes[1];                  // 1600000
    const int nb = (N + BUCKET - 1) / BUCKET;   // 391
    const int nBin = (E + EPB - 1) / EPB;       // 196
    const int nAgg = (N + AGG_W - 1) / AGG_W;   // 1563

    // ---- workspace layout with explicit alignment ----
    char* p = (char*)d_ws;
    auto alloc = [&](size_t bytes, size_t align) -> void* {
        size_t a = ((size_t)p + align - 1) & ~(align - 1);
        p = (char*)(a + bytes);
        return (void*)a;
    };
    unsigned char* X1q = (unsigned char*)alloc(64 * (size_t)N, 16);
    unsigned int* binnedD = (unsigned int*)alloc(4 * (size_t)E, 16);
    unsigned int* binnedS = (unsigned int*)alloc(4 * (size_t)E, 16);
    int*   sortedSrc = (int*)alloc(4 * (size_t)E, 16);
    int*   cntD   = (int*)alloc(4 * MAXB, 16);          // \ zeroed together
    int*   cntS   = (int*)alloc(4 * MAXB, 4);           // /
    int*   baseD  = (int*)alloc(4 * (MAXB + 1), 4);
    int*   curD   = (int*)alloc(4 * MAXB, 4);
    int*   baseS  = (int*)alloc(4 * (MAXB + 1), 4);
    int*   curS   = (int*)alloc(4 * MAXB, 4);
    int*   nodeOff  = (int*)alloc(4 * ((size_t)N + 1), 4);
    float* norm_in  = (float*)alloc(4 * (size_t)N, 4);
    float* norm_out = (float*)alloc(4 * (size_t)N, 4);
    float* wsum     = (float*)alloc(4 * (size_t)N, 4);
    float* partials = (float*)alloc(4 * (size_t)nAgg * 64, 16);
    double* red     = (double*)alloc(8 * (size_t)NRED * 64, 8);

    // only the bucket-count accumulators are read-before-write
    hipMemsetAsync(cntD, 0, 2 * MAXB * sizeof(int), stream);

    k_bhist<<<nBin, 256, 0, stream>>>(src, dst, cntS, cntD, E, nb);

    k_bucketscan2<<<1, 1024, 0, stream>>>(cntD, cntS, baseD, curD, baseS, curS, nb, E);

    k_bin2<<<nBin, 256, 0, stream>>>(src, dst, curD, curS, binnedD, binnedS, E, nb);

    k_sortD<<<nb, 256, 0, stream>>>(binnedD, baseD, sortedSrc, nodeOff, norm_in, N, E);
    k_wsum <<<nb, 256, 0, stream>>>(binnedS, baseS, norm_in, wsum, norm_out, N);

    k_gemm1<<<(N + 63) / 64, 256, 0, stream>>>(in_feat, W1, norm_out, X1q, N);

    k_agg<<<nAgg, 256, 0, stream>>>(X1q, sortedSrc, nodeOff, norm_in, norm_out,
                                    wsum, b1, partials, N);

    k_red  <<<NRED, 256, 0, stream>>>(partials, red, nAgg);
    k_final<<<1, 256, 0, stream>>>(red, W2, b2, out, N);
}